// Round 2
// baseline (496.557 us; speedup 1.0000x reference)
//
#include <hip/hip_runtime.h>

#define HW 3136      // 56*56
#define SHS 120      // sH row stride: 112 px + 8 pad (write residues cover all 16 even slots -> b64 floor)

// One fused residual-stage: grouped3x3 conv + bias + BN + ReLU -> (LDS) -> grouped1x1 conv
// + bias + BN + ReLU -> global.
// v2: 2-row tiles + no sW staging => LDS 30.7 KB/block => 5 blocks/CU (was 2).
// pw weights read from global (16 KB/group, L1-resident). XCD-aware decode co-locates
// the 4 g-blocks sharing one input tile on one XCD's L2.
__global__ __launch_bounds__(256, 5) void fused_stage(
    const float* __restrict__ in,    // [32,256,56,56]
    const float* __restrict__ gw,    // [4,64,4,3,3]  (i,k,cc,dy,dx)
    const float* __restrict__ gb,    // [256] flat (i*64+k)
    const float* __restrict__ bnag, const float* __restrict__ bnab,
    const float* __restrict__ bnam, const float* __restrict__ bnav,
    const float* __restrict__ pw,    // [256,64]
    const float* __restrict__ pb,    // [256]
    const float* __restrict__ bnbg, const float* __restrict__ bnbb,
    const float* __restrict__ bnbm, const float* __restrict__ bnbv,
    float* __restrict__ out)         // [32,256,56,56]
{
    __shared__ float sH[64 * SHS];   // 30720 B: intermediate h[k][r*56+x]

    const int tid = threadIdx.x;

    // XCD-aware decode: blockIdx%8 = XCD (round-robin dispatch heuristic). The 4
    // g-blocks for one (b,t) input tile are 8 apart -> same XCD, adjacent in time,
    // so the 4x re-read of the 256ch x 4row input tile hits that XCD's L2.
    const int idx  = blockIdx.x;
    const int xcd  = idx & 7;
    const int qq   = idx >> 3;
    const int g    = qq & 3;         // conv-index / pw-group
    const int slot = qq >> 2;        // 0..111
    const int u    = slot * 8 + xcd; // 0..895
    const int b    = u / 28;
    const int t    = u - b * 28;     // 2-row tile 0..27
    const int y0   = t * 2;

    // ---- phase 1: grouped 3x3 conv for conv-index g, all 64 groups k, 2 rows ----
    const int k  = tid >> 2;         // 0..63 group (intermediate channel g*64+k)
    const int xs = tid & 3;          // x-strip of 14
    const int x0 = xs * 14;

    float acc[2][14];
#pragma unroll
    for (int r = 0; r < 2; ++r)
#pragma unroll
        for (int xx = 0; xx < 14; ++xx) acc[r][xx] = 0.f;

    const float* wkp = gw + (size_t)(g * 64 + k) * 36;

#pragma unroll
    for (int cc = 0; cc < 4; ++cc) {
        float wr9[9];                // only 9 live weight regs (was 36)
#pragma unroll
        for (int j = 0; j < 9; ++j) wr9[j] = wkp[cc * 9 + j];
        const float* chp = in + ((size_t)(b * 256 + k * 4 + cc)) * HW;
#pragma unroll
        for (int ry = 0; ry < 4; ++ry) {
            const int gy = y0 - 1 + ry;          // block-uniform after unroll
            if ((unsigned)gy >= 56u) continue;   // zero-pad rows
            const float* rp = chp + gy * 56;
            float rr[16];                        // cols x0-1 .. x0+14
            rr[0]  = (x0 > 0)       ? rp[x0 - 1]  : 0.f;
            rr[15] = (x0 + 14 < 56) ? rp[x0 + 14] : 0.f;
#pragma unroll
            for (int j = 0; j < 7; ++j) {
                float2 v = *(const float2*)(rp + x0 + 2 * j);  // 8B-aligned
                rr[1 + 2*j] = v.x; rr[2 + 2*j] = v.y;
            }
#pragma unroll
            for (int r = 0; r < 2; ++r) {
                const int wi = ry - r;               // weight row index
                if (wi < 0 || wi > 2) continue;      // dead-code after unroll
                const float w0 = wr9[wi*3 + 0];
                const float w1 = wr9[wi*3 + 1];
                const float w2 = wr9[wi*3 + 2];
#pragma unroll
                for (int xx = 0; xx < 14; ++xx)
                    acc[r][xx] = fmaf(w2, rr[xx+2],
                                 fmaf(w1, rr[xx+1],
                                 fmaf(w0, rr[xx], acc[r][xx])));
            }
        }
    }

    // bias + BN-a + ReLU -> sH
    {
        const int c = g * 64 + k;
        const float sc = bnag[c] * rsqrtf(bnav[c] + 1e-5f);
        const float sh = fmaf(gb[c], sc, bnab[c] - bnam[c] * sc);
#pragma unroll
        for (int r = 0; r < 2; ++r)
#pragma unroll
            for (int j = 0; j < 7; ++j) {
                float v0 = fmaxf(fmaf(acc[r][2*j],   sc, sh), 0.f);
                float v1 = fmaxf(fmaf(acc[r][2*j+1], sc, sh), 0.f);
                *(float2*)&sH[k * SHS + r * 56 + x0 + 2*j] = make_float2(v0, v1);
            }
    }
    __syncthreads();

    // ---- phase 2: 64x112 = W[64x64] * sH[64x112] GEMM, 2-out x 14-px tile ----
    const int og = tid >> 3;         // 0..31 -> out channels og*2, og*2+1
    const int pg = tid & 7;          // 0..7  -> px p0..p0+13
    const int p0 = pg * 14;

    float a2[2][14];
#pragma unroll
    for (int i = 0; i < 2; ++i)
#pragma unroll
        for (int xx = 0; xx < 14; ++xx) a2[i][xx] = 0.f;

    const float* wp0 = pw + (size_t)(g * 64 + og * 2) * 64;  // row o ; row o+1 at +64

#pragma unroll 2
    for (int c = 0; c < 64; c += 4) {
        const float4 w0 = *(const float4*)(wp0 + c);         // L1-hit broadcast
        const float4 w1 = *(const float4*)(wp0 + 64 + c);
        const float w0a[4] = {w0.x, w0.y, w0.z, w0.w};
        const float w1a[4] = {w1.x, w1.y, w1.z, w1.w};
#pragma unroll
        for (int q2 = 0; q2 < 4; ++q2) {
            float hr[14];
#pragma unroll
            for (int j = 0; j < 7; ++j) {
                float2 v = *(const float2*)&sH[(c + q2) * SHS + p0 + 2*j]; // 8-way bcast, conflict-free
                hr[2*j] = v.x; hr[2*j+1] = v.y;
            }
            const float wa = w0a[q2];
            const float wb = w1a[q2];
#pragma unroll
            for (int xx = 0; xx < 14; ++xx) {
                a2[0][xx] = fmaf(wa, hr[xx], a2[0][xx]);
                a2[1][xx] = fmaf(wb, hr[xx], a2[1][xx]);
            }
        }
    }

    // bias + BN-b + ReLU -> global
    const int orow = y0 + ((p0 >= 56) ? 1 : 0);
    const int ox   = (p0 >= 56) ? p0 - 56 : p0;
#pragma unroll
    for (int i = 0; i < 2; ++i) {
        const int o = g * 64 + og * 2 + i;
        const float sc = bnbg[o] * rsqrtf(bnbv[o] + 1e-5f);
        const float sh = fmaf(pb[o], sc, bnbb[o] - bnbm[o] * sc);
        float* op = out + ((size_t)(b * 256 + o)) * HW + orow * 56 + ox;
#pragma unroll
        for (int j = 0; j < 7; ++j) {
            float v0 = fmaxf(fmaf(a2[i][2*j],   sc, sh), 0.f);
            float v1 = fmaxf(fmaf(a2[i][2*j+1], sc, sh), 0.f);
            *(float2*)(op + 2*j) = make_float2(v0, v1);
        }
    }
}

extern "C" void kernel_launch(void* const* d_in, const int* in_sizes, int n_in,
                              void* d_out, int out_size, void* d_ws, size_t ws_size,
                              hipStream_t stream) {
    const float* x     = (const float*)d_in[0];
    const float* w1    = (const float*)d_in[1];
    const float* b1    = (const float*)d_in[2];
    const float* bn1ag = (const float*)d_in[3];
    const float* bn1ab = (const float*)d_in[4];
    const float* bn1am = (const float*)d_in[5];
    const float* bn1av = (const float*)d_in[6];
    const float* pw1   = (const float*)d_in[7];
    const float* pb1   = (const float*)d_in[8];
    const float* bn1bg = (const float*)d_in[9];
    const float* bn1bb = (const float*)d_in[10];
    const float* bn1bm = (const float*)d_in[11];
    const float* bn1bv = (const float*)d_in[12];
    const float* w2    = (const float*)d_in[13];
    const float* b2    = (const float*)d_in[14];
    const float* bn2ag = (const float*)d_in[15];
    const float* bn2ab = (const float*)d_in[16];
    const float* bn2am = (const float*)d_in[17];
    const float* bn2av = (const float*)d_in[18];
    const float* pw2   = (const float*)d_in[19];
    const float* pb2   = (const float*)d_in[20];
    const float* bn2bg = (const float*)d_in[21];
    const float* bn2bb = (const float*)d_in[22];
    const float* bn2bm = (const float*)d_in[23];
    const float* bn2bv = (const float*)d_in[24];

    float* mid  = (float*)d_ws;      // 32*256*56*56*4 = 102,760,448 B
    float* outp = (float*)d_out;

    const int grid = 32 * 4 * 28;    // (b, g, 2-row tile) via XCD-aware decode

    fused_stage<<<grid, 256, 0, stream>>>(x,   w1, b1, bn1ag, bn1ab, bn1am, bn1av,
                                          pw1, pb1, bn1bg, bn1bb, bn1bm, bn1bv, mid);
    fused_stage<<<grid, 256, 0, stream>>>(mid, w2, b2, bn2ag, bn2ab, bn2am, bn2av,
                                          pw2, pb2, bn2bg, bn2bb, bn2bm, bn2bv, outp);
}